// Round 15
// baseline (95.071 us; speedup 1.0000x reference)
//
#include <hip/hip_runtime.h>
#include <hip/hip_bf16.h>

#define D_MODEL 1024
#define HEAD 64
#define TSEQ 2048
#define NB 4
#define BT (NB * TSEQ)

typedef __bf16 bf16x8 __attribute__((ext_vector_type(8)));
typedef __bf16 bf16x4 __attribute__((ext_vector_type(4)));
typedef float f32x4 __attribute__((ext_vector_type(4)));

#define LOG2E 1.44269504088896f

__device__ inline unsigned pkbf(float a, float b) {
    union { __bf16 h[2]; unsigned u; } t;
    t.h[0] = (__bf16)a; t.h[1] = (__bf16)b;
    return t.u;
}

// ---------------------------------------------------------------------------
// Kernel 0: W transpose + bf16 convert (unchanged).
// ---------------------------------------------------------------------------
__global__ __launch_bounds__(256) void wt_kernel(
    const float* __restrict__ Wq, const float* __restrict__ Wk,
    const float* __restrict__ Wv, __bf16* __restrict__ wt)
{
    __shared__ float tile[64][65];
    int tsel = blockIdx.x >> 4;
    int k0 = (blockIdx.x & 15) * 64;
    const float* W = tsel == 0 ? Wq : (tsel == 1 ? Wk : Wv);
    int tid = threadIdx.x;
#pragma unroll
    for (int i = 0; i < 16; ++i) {
        int idx = i * 256 + tid;
        int k = idx >> 6, c = idx & 63;
        tile[k][c] = W[(size_t)(k0 + k) * 64 + c];
    }
    __syncthreads();
#pragma unroll
    for (int i = 0; i < 16; ++i) {
        int idx = i * 256 + tid;
        int c = idx >> 6, k = idx & 63;
        wt[(size_t)(tsel * 64 + c) * 1024 + k0 + k] = (__bf16)tile[k][c];
    }
}

// ---------------------------------------------------------------------------
// Kernel 1: QKV MFMA GEMM (byte-identical to round 14).
// ROUND 15: launched TWICE (idempotent — pure function of x/wt/biases,
// overwrites qs/ks/vT deterministically). dur_us delta vs round 14's 64.7
// = qkv_gemm's exact duration. Same attribution method as round 13 (attn).
// ---------------------------------------------------------------------------
__global__ __launch_bounds__(512, 4) void qkv_gemm(
    const float* __restrict__ x, const __bf16* __restrict__ wt,
    const float* __restrict__ bq, const float* __restrict__ bk, const float* __restrict__ bv,
    __bf16* __restrict__ qs, __bf16* __restrict__ ks, __bf16* __restrict__ vT)
{
    __shared__ f32x4 red[8][6][64];   // 48 KB [kslice][coltile][lane]

    int d = blockIdx.x;
    int bi = d >> 3;
    int strip = (d & 7) * 64 + (bi >> 1);
    int ch = bi & 1;
    int r0 = strip * 16;

    int tid = threadIdx.x;
    int w = tid >> 6;                 // 0..7 = K slice
    int lane = tid & 63;
    int c16 = lane & 15, g = lane >> 4;

    const float* xbase = x + (size_t)(r0 + c16) * D_MODEL + w * 128 + g * 8;
    const __bf16* wbase = wt + (size_t)(ch * 96 + c16) * D_MODEL + w * 128 + g * 8;

    // ---- preload iteration 0: all 8 loads in flight ----
    float4 xa = *(const float4*)(xbase);
    float4 xb = *(const float4*)(xbase + 4);
    bf16x8 w0 = *(const bf16x8*)(wbase + (size_t)0 * 16 * D_MODEL);
    bf16x8 w1 = *(const bf16x8*)(wbase + (size_t)1 * 16 * D_MODEL);
    bf16x8 w2 = *(const bf16x8*)(wbase + (size_t)2 * 16 * D_MODEL);
    bf16x8 w3 = *(const bf16x8*)(wbase + (size_t)3 * 16 * D_MODEL);
    bf16x8 w4 = *(const bf16x8*)(wbase + (size_t)4 * 16 * D_MODEL);
    bf16x8 w5 = *(const bf16x8*)(wbase + (size_t)5 * 16 * D_MODEL);

    f32x4 acc[6];
#pragma unroll
    for (int j = 0; j < 6; ++j) acc[j] = (f32x4){0.f, 0.f, 0.f, 0.f};

#pragma unroll
    for (int kt = 0; kt < 4; ++kt) {
        float4 xan, xbn;
        bf16x8 n0, n1, n2, n3, n4, n5;
        if (kt < 3) {
            const float*  xn = xbase + (kt + 1) * 32;
            const __bf16* wn = wbase + (kt + 1) * 32;
            xan = *(const float4*)(xn);
            xbn = *(const float4*)(xn + 4);
            n0 = *(const bf16x8*)(wn + (size_t)0 * 16 * D_MODEL);
            n1 = *(const bf16x8*)(wn + (size_t)1 * 16 * D_MODEL);
            n2 = *(const bf16x8*)(wn + (size_t)2 * 16 * D_MODEL);
            n3 = *(const bf16x8*)(wn + (size_t)3 * 16 * D_MODEL);
            n4 = *(const bf16x8*)(wn + (size_t)4 * 16 * D_MODEL);
            n5 = *(const bf16x8*)(wn + (size_t)5 * 16 * D_MODEL);
        }

        bf16x8 af;
        af[0] = (__bf16)xa.x; af[1] = (__bf16)xa.y;
        af[2] = (__bf16)xa.z; af[3] = (__bf16)xa.w;
        af[4] = (__bf16)xb.x; af[5] = (__bf16)xb.y;
        af[6] = (__bf16)xb.z; af[7] = (__bf16)xb.w;

        acc[0] = __builtin_amdgcn_mfma_f32_16x16x32_bf16(af, w0, acc[0], 0, 0, 0);
        acc[1] = __builtin_amdgcn_mfma_f32_16x16x32_bf16(af, w1, acc[1], 0, 0, 0);
        acc[2] = __builtin_amdgcn_mfma_f32_16x16x32_bf16(af, w2, acc[2], 0, 0, 0);
        acc[3] = __builtin_amdgcn_mfma_f32_16x16x32_bf16(af, w3, acc[3], 0, 0, 0);
        acc[4] = __builtin_amdgcn_mfma_f32_16x16x32_bf16(af, w4, acc[4], 0, 0, 0);
        acc[5] = __builtin_amdgcn_mfma_f32_16x16x32_bf16(af, w5, acc[5], 0, 0, 0);

        if (kt < 3) {
            xa = xan; xb = xbn;
            w0 = n0; w1 = n1; w2 = n2; w3 = n3; w4 = n4; w5 = n5;
        }
    }

#pragma unroll
    for (int j = 0; j < 6; ++j) red[w][j][lane] = acc[j];
    __syncthreads();

    if (w < 6) {
        int j = w;
        f32x4 s = red[0][j][lane];
#pragma unroll
        for (int sw = 1; sw < 8; ++sw) s += red[sw][j][lane];

        int col = ch * 96 + j * 16 + c16;   // global column 0..191
        int tsel = col >> 6;                // 0=q 1=k 2=v
        int cm = col & 63;                  // column within its matrix
        const float* bias = tsel == 0 ? bq : (tsel == 1 ? bk : bv);
        float bval = bias[cm];
        if (tsel == 0) {
#pragma unroll
            for (int r = 0; r < 4; ++r)
                qs[(size_t)(r0 + g * 4 + r) * HEAD + cm] = (__bf16)((s[r] + bval) * (0.03125f * LOG2E));
        } else if (tsel == 1) {
#pragma unroll
            for (int r = 0; r < 4; ++r)
                ks[(size_t)(r0 + g * 4 + r) * HEAD + cm] = (__bf16)(s[r] + bval);
        } else {
#pragma unroll
            for (int r = 0; r < 4; ++r) {
                int row = r0 + g * 4 + r;
                int b = row >> 11, t = row & (TSEQ - 1);
                vT[(size_t)(b * HEAD + cm) * TSEQ + t] = (__bf16)(s[r] + bval);
            }
        }
    }
}

// ---------------------------------------------------------------------------
// Kernel 2: flash attention (unchanged from round 12/14; measured 24.3 µs).
// ---------------------------------------------------------------------------
__global__ __launch_bounds__(512, 4) void attn_mfma(
    const __bf16* __restrict__ qs, const __bf16* __restrict__ ks,
    const __bf16* __restrict__ vT, float* __restrict__ out)
{
    __shared__ __align__(16) f32x4 ocomb[8][4][64];     // 32 KB [wave][hh][lane]
    __shared__ float mcomb[8][16];                      // [wave][qrow]
    __shared__ float lcomb[8][16];

    int d = blockIdx.x;
    int xcd = d & 7;
    int slot = d >> 3;                  // 0..63
    int b = xcd >> 1;
    int qt = ((xcd & 1) ? 127 : 126) - 2 * slot;   // heavy-first, parity split
    int qb = qt * 16;

    int tid = threadIdx.x;
    int w = tid >> 6;                   // 0..7
    int lane = tid & 63;
    int g = lane >> 4;
    int c16 = lane & 15;

    const __bf16* qsb = qs + (size_t)(b * TSEQ + qb) * HEAD;
    const __bf16* kb_ = ks + (size_t)b * TSEQ * HEAD;
    const __bf16* vb_ = vT + (size_t)b * HEAD * TSEQ;

    bf16x8 qf0 = *(const bf16x8*)(qsb + c16 * HEAD + g * 8);
    bf16x8 qf1 = *(const bf16x8*)(qsb + c16 * HEAD + 32 + g * 8);

    f32x4 o0 = {0.f, 0.f, 0.f, 0.f}, o1 = o0, o2 = o0, o3 = o0;
    float m = -3.0e38f, l = 0.f;

    int nt = (qb + 47) >> 5;            // number of 32-key tiles
    int qrow = qb + c16;

    // ---- preload K for first tile ----
    bf16x8 k00c, k01c, k10c, k11c;
    if (w < nt) {
        const __bf16* kr0 = kb_ + (size_t)(w * 32 + c16) * HEAD + g * 8;
        k00c = *(const bf16x8*)(kr0);
        k01c = *(const bf16x8*)(kr0 + 32);
        const __bf16* kr1 = kr0 + 16 * HEAD;
        k10c = *(const bf16x8*)(kr1);
        k11c = *(const bf16x8*)(kr1 + 32);
    }

    for (int ti = w; ti < nt; ti += 8) {
        int kbase = ti * 32;

        // ---- early-issue V for this tile ----
        const __bf16* vbase = vb_ + kbase + g * 8;
        bf16x8 v0 = *(const bf16x8*)(vbase + (size_t)(c16) * TSEQ);
        bf16x8 v1 = *(const bf16x8*)(vbase + (size_t)(c16 + 16) * TSEQ);
        bf16x8 v2 = *(const bf16x8*)(vbase + (size_t)(c16 + 32) * TSEQ);
        bf16x8 v3 = *(const bf16x8*)(vbase + (size_t)(c16 + 48) * TSEQ);

        // ---- prefetch next K tile ----
        bool pf = (ti + 8) < nt;
        bf16x8 k00n, k01n, k10n, k11n;
        if (pf) {
            const __bf16* kr0 = kb_ + (size_t)(kbase + 256 + c16) * HEAD + g * 8;
            k00n = *(const bf16x8*)(kr0);
            k01n = *(const bf16x8*)(kr0 + 32);
            const __bf16* kr1 = kr0 + 16 * HEAD;
            k10n = *(const bf16x8*)(kr1);
            k11n = *(const bf16x8*)(kr1 + 32);
        }

        // ---- QK^T (swapped) ----
        f32x4 z = {0.f, 0.f, 0.f, 0.f};
        f32x4 s0 = __builtin_amdgcn_mfma_f32_16x16x32_bf16(k00c, qf0, z, 0, 0, 0);
        s0 = __builtin_amdgcn_mfma_f32_16x16x32_bf16(k01c, qf1, s0, 0, 0, 0);
        f32x4 s1 = __builtin_amdgcn_mfma_f32_16x16x32_bf16(k10c, qf0, z, 0, 0, 0);
        s1 = __builtin_amdgcn_mfma_f32_16x16x32_bf16(k11c, qf1, s1, 0, 0, 0);

        // ---- causal mask ----
        if (kbase + 31 > qb) {
#pragma unroll
            for (int r = 0; r < 4; ++r) {
                if (kbase + 4 * g + r > qrow)      s0[r] = -3.0e38f;
                if (kbase + 16 + 4 * g + r > qrow) s1[r] = -3.0e38f;
            }
        }

        // ---- online softmax ----
        float vmax = fmaxf(fmaxf(fmaxf(s0[0], s0[1]), fmaxf(s0[2], s0[3])),
                           fmaxf(fmaxf(s1[0], s1[1]), fmaxf(s1[2], s1[3])));
        vmax = fmaxf(vmax, __shfl_xor(vmax, 16, 64));
        vmax = fmaxf(vmax, __shfl_xor(vmax, 32, 64));
        float mn = fmaxf(m, vmax);
        float al = exp2f(m - mn);
        m = mn;

        float p0[4], p1[4];
        float rsum = 0.f;
#pragma unroll
        for (int r = 0; r < 4; ++r) {
            p0[r] = exp2f(s0[r] - m);
            p1[r] = exp2f(s1[r] - m);
            rsum += p0[r] + p1[r];
        }
        rsum += __shfl_xor(rsum, 16, 64);
        rsum += __shfl_xor(rsum, 32, 64);
        l = l * al + rsum;
        o0 *= al; o1 *= al; o2 *= al; o3 *= al;

        // ---- P^T redistribution ----
        unsigned pk[4];
        pk[0] = pkbf(p0[0], p0[1]); pk[1] = pkbf(p0[2], p0[3]);
        pk[2] = pkbf(p1[0], p1[1]); pk[3] = pkbf(p1[2], p1[3]);

        union { unsigned u[4]; bf16x8 v; } pb;
#pragma unroll
        for (int t = 0; t < 4; ++t) {
            int srcl = c16 + 16 * ((2 * g + (t >> 1)) & 3);
            unsigned lo = (unsigned)__shfl((int)pk[t & 1], srcl, 64);
            unsigned hi = (unsigned)__shfl((int)pk[2 + (t & 1)], srcl, 64);
            pb.u[t] = (g < 2) ? lo : hi;
        }

        // ---- PV ----
        o0 = __builtin_amdgcn_mfma_f32_16x16x32_bf16(v0, pb.v, o0, 0, 0, 0);
        o1 = __builtin_amdgcn_mfma_f32_16x16x32_bf16(v1, pb.v, o1, 0, 0, 0);
        o2 = __builtin_amdgcn_mfma_f32_16x16x32_bf16(v2, pb.v, o2, 0, 0, 0);
        o3 = __builtin_amdgcn_mfma_f32_16x16x32_bf16(v3, pb.v, o3, 0, 0, 0);

        if (pf) { k00c = k00n; k01c = k01n; k10c = k10n; k11c = k11n; }
    }

    // ---- publish partials ----
    ocomb[w][0][lane] = o0;
    ocomb[w][1][lane] = o1;
    ocomb[w][2][lane] = o2;
    ocomb[w][3][lane] = o3;
    if (g == 0) {
        mcomb[w][c16] = m;
        lcomb[w][c16] = l;
    }
    __syncthreads();

    // ---- combine ----
    if (w < 4) {
        float M = mcomb[0][c16];
#pragma unroll
        for (int sw = 1; sw < 8; ++sw) M = fmaxf(M, mcomb[sw][c16]);
        f32x4 O = {0.f, 0.f, 0.f, 0.f};
        float L = 0.f;
#pragma unroll
        for (int sw = 0; sw < 8; ++sw) {
            float e = exp2f(mcomb[sw][c16] - M);
            L += lcomb[sw][c16] * e;
            f32x4 po = ocomb[sw][w][lane];
            O[0] += po[0] * e; O[1] += po[1] * e;
            O[2] += po[2] * e; O[3] += po[3] * e;
        }
        float rcp = 1.0f / L;
        f32x4 res = {O[0] * rcp, O[1] * rcp, O[2] * rcp, O[3] * rcp};
        *(f32x4*)(out + (size_t)(b * TSEQ + qb + c16) * HEAD + w * 16 + g * 4) = res;
    }
}

extern "C" void kernel_launch(void* const* d_in, const int* in_sizes, int n_in,
                              void* d_out, int out_size, void* d_ws, size_t ws_size,
                              hipStream_t stream) {
    const float* x  = (const float*)d_in[0];
    const float* Wk = (const float*)d_in[1];
    const float* Wq = (const float*)d_in[2];
    const float* Wv = (const float*)d_in[3];
    const float* bk = (const float*)d_in[4];
    const float* bq = (const float*)d_in[5];
    const float* bv = (const float*)d_in[6];
    float* out = (float*)d_out;

    __bf16* qs = (__bf16*)d_ws;                        // [BT][64]        1 MB
    __bf16* ks = qs + (size_t)BT * HEAD;               // [BT][64]        1 MB
    __bf16* vT = ks + (size_t)BT * HEAD;               // [NB][64][TSEQ]  1 MB
    __bf16* wt = vT + (size_t)BT * HEAD;               // [192][1024]     384 KB

    wt_kernel<<<48, 256, 0, stream>>>(Wq, Wk, Wv, wt);
    // Launched twice (idempotent) — attribution measurement: dur_us delta
    // vs round 14's 64.7 µs = qkv_gemm's exact duration.
    qkv_gemm<<<1024, 512, 0, stream>>>(x, wt, bq, bk, bv, qs, ks, vT);
    qkv_gemm<<<1024, 512, 0, stream>>>(x, wt, bq, bk, bv, qs, ks, vT);
    attn_mfma<<<512, 512, 0, stream>>>(qs, ks, vT, out);
}

// Round 16
// 49.653 us; speedup vs baseline: 1.9147x; 1.9147x over previous
//
#include <hip/hip_runtime.h>
#include <hip/hip_bf16.h>

#define D_MODEL 1024
#define HEAD 64
#define TSEQ 2048
#define NB 4
#define BT (NB * TSEQ)

typedef __bf16 bf16x8 __attribute__((ext_vector_type(8)));
typedef __bf16 bf16x4 __attribute__((ext_vector_type(4)));
typedef float f32x4 __attribute__((ext_vector_type(4)));

#define LOG2E 1.44269504088896f

__device__ inline unsigned pkbf(float a, float b) {
    union { __bf16 h[2]; unsigned u; } t;
    t.h[0] = (__bf16)a; t.h[1] = (__bf16)b;
    return t.u;
}

// ---------------------------------------------------------------------------
// Kernel 0 (ROUND 16): W -> B-fragment-major bf16.
// wtf[((jt*32 + ktile)*64 + lane)*8 + i] = W_tsel[ktile*32 + g*8 + i][jt*16+c16]
// (lane = c16 + 16*g, jt = global 16-col tile 0..11, tsel = jt>>2).
// Makes every GEMM B-load a contiguous 1 KB wave load (was: 64 lines at
// 2 KB lane stride — the scatter that dominated qkv per R15 attribution).
// Block = (jt, 256-k chunk): 12*4 = 48 blocks.
// ---------------------------------------------------------------------------
__global__ __launch_bounds__(256) void wt_kernel(
    const float* __restrict__ Wq, const float* __restrict__ Wk,
    const float* __restrict__ Wv, __bf16* __restrict__ wtf)
{
    __shared__ float ws_[256][20];   // [k local][16 cols + pad4] = 20 KB

    int jt = blockIdx.x >> 2;        // 0..11
    int chunk = blockIdx.x & 3;      // 0..3 (256 k each)
    int tsel = jt >> 2;
    int colbase = (jt & 3) * 16;
    const float* W = tsel == 0 ? Wq : (tsel == 1 ? Wk : Wv);

    int t = threadIdx.x;
    // load 256 k-rows x 16 cols = 1024 float4 (4 per k-row)
#pragma unroll
    for (int i = 0; i < 4; ++i) {
        int f4 = t + 256 * i;
        int krow = f4 >> 2, cg = f4 & 3;
        float4 v = *(const float4*)(W + (size_t)(chunk * 256 + krow) * 64 + colbase + cg * 4);
        *(float4*)(&ws_[krow][cg * 4]) = v;   // row base 80 B: 16-aligned
    }
    __syncthreads();

    // emit 8 ktiles x 64 lanes = 512 fragment slots (16 B each); 2 per thread
#pragma unroll
    for (int sidx = 0; sidx < 2; ++sidx) {
        int s = t + 256 * sidx;
        int kk = s >> 6;             // local ktile 0..7
        int lane = s & 63;
        int c16 = lane & 15, g = lane >> 4;
        bf16x8 o;
#pragma unroll
        for (int i = 0; i < 8; ++i)
            o[i] = (__bf16)ws_[kk * 32 + g * 8 + i][c16];
        *(bf16x8*)(wtf + ((size_t)(jt * 32 + chunk * 8 + kk) * 64 + lane) * 8) = o;
    }
}

// ---------------------------------------------------------------------------
// Kernel 1 (ROUND 16): QKV GEMM with coalesced load paths.
//  - x strip (16x1024) staged COALESCED into LDS as bf16 (+8 pad/row ->
//    A-frag ds_read_b128 is <=2-way bank = free). Was: 64-line scatter.
//  - B-frags from wtf: contiguous 1 KB wave loads. Was: 64-line scatter.
//  - LDS union: staging buffer (33 KB) reused as reduce buffer (48 KB).
// Grid/K-split/epilogue unchanged from R11/R14.
// ---------------------------------------------------------------------------
#define XPITCH 1032   // 1024 + 8 bf16 pad

__global__ __launch_bounds__(512, 4) void qkv_gemm(
    const float* __restrict__ x, const __bf16* __restrict__ wtf,
    const float* __restrict__ bq, const float* __restrict__ bk, const float* __restrict__ bv,
    __bf16* __restrict__ qs, __bf16* __restrict__ ks, __bf16* __restrict__ vT)
{
    __shared__ __align__(16) char lds_raw[49152];             // 48 KB
    __bf16 (*xls)[XPITCH] = (__bf16(*)[XPITCH])lds_raw;       // 33 KB (staging)
    f32x4 (*red)[6][64]   = (f32x4(*)[6][64])lds_raw;         // 48 KB (reduce)

    int d = blockIdx.x;
    int bi = d >> 3;
    int strip = (d & 7) * 64 + (bi >> 1);   // XCD-chunked rows
    int ch = bi & 1;
    int r0 = strip * 16;

    int tid = threadIdx.x;
    int w = tid >> 6;                 // 0..7 = K slice (128 k each)
    int lane = tid & 63;
    int c16 = lane & 15, g = lane >> 4;

    // ---- stage x[16][1024] -> LDS bf16, fully coalesced ----
#pragma unroll
    for (int i = 0; i < 8; ++i) {
        int f4 = tid + 512 * i;           // 0..4095
        int row = f4 >> 8;                // 256 float4 per row
        int k = (f4 & 255) * 4;
        float4 v = *(const float4*)(x + (size_t)(r0 + row) * D_MODEL + k);
        bf16x4 o;
        o[0] = (__bf16)v.x; o[1] = (__bf16)v.y;
        o[2] = (__bf16)v.z; o[3] = (__bf16)v.w;
        *(bf16x4*)(&xls[row][k]) = o;     // 8B store, aligned
    }
    __syncthreads();

    f32x4 acc[6];
#pragma unroll
    for (int j = 0; j < 6; ++j) acc[j] = (f32x4){0.f, 0.f, 0.f, 0.f};

#pragma unroll
    for (int kt = 0; kt < 4; ++kt) {
        int ktile = w * 4 + kt;           // 0..31
        // A-frag from LDS: lane(c16,g) = x[r0+c16][ktile*32 + g*8 ..+8]
        bf16x8 af = *(const bf16x8*)(&xls[c16][ktile * 32 + g * 8]);
        // B-frags: contiguous 1 KB wave loads
        const __bf16* wb = wtf + ((size_t)ktile * 64 + lane) * 8;
#pragma unroll
        for (int j = 0; j < 6; ++j) {
            bf16x8 bfr = *(const bf16x8*)(wb + (size_t)(ch * 6 + j) * 32 * 64 * 8);
            acc[j] = __builtin_amdgcn_mfma_f32_16x16x32_bf16(af, bfr, acc[j], 0, 0, 0);
        }
    }

    __syncthreads();                      // xls dead; safe to overwrite as red
#pragma unroll
    for (int j = 0; j < 6; ++j) red[w][j][lane] = acc[j];
    __syncthreads();

    if (w < 6) {
        int j = w;
        f32x4 s = red[0][j][lane];
#pragma unroll
        for (int sw = 1; sw < 8; ++sw) s += red[sw][j][lane];

        int col = ch * 96 + j * 16 + c16;   // global column 0..191
        int tsel = col >> 6;                // 0=q 1=k 2=v
        int cm = col & 63;
        const float* bias = tsel == 0 ? bq : (tsel == 1 ? bk : bv);
        float bval = bias[cm];
        if (tsel == 0) {
#pragma unroll
            for (int r = 0; r < 4; ++r)
                qs[(size_t)(r0 + g * 4 + r) * HEAD + cm] = (__bf16)((s[r] + bval) * (0.03125f * LOG2E));
        } else if (tsel == 1) {
#pragma unroll
            for (int r = 0; r < 4; ++r)
                ks[(size_t)(r0 + g * 4 + r) * HEAD + cm] = (__bf16)(s[r] + bval);
        } else {
#pragma unroll
            for (int r = 0; r < 4; ++r) {
                int row = r0 + g * 4 + r;
                int b = row >> 11, t = row & (TSEQ - 1);
                vT[(size_t)(b * HEAD + cm) * TSEQ + t] = (__bf16)(s[r] + bval);
            }
        }
    }
}

// ---------------------------------------------------------------------------
// Kernel 2: flash attention (byte-identical to R12/R14; measured 24.3 µs).
// Its K/V loads are also 64-line scatters — fixed NEXT round via
// fragment-major ks/vT if this round confirms the scatter theory.
// ---------------------------------------------------------------------------
__global__ __launch_bounds__(512, 4) void attn_mfma(
    const __bf16* __restrict__ qs, const __bf16* __restrict__ ks,
    const __bf16* __restrict__ vT, float* __restrict__ out)
{
    __shared__ __align__(16) f32x4 ocomb[8][4][64];     // 32 KB [wave][hh][lane]
    __shared__ float mcomb[8][16];                      // [wave][qrow]
    __shared__ float lcomb[8][16];

    int d = blockIdx.x;
    int xcd = d & 7;
    int slot = d >> 3;                  // 0..63
    int b = xcd >> 1;
    int qt = ((xcd & 1) ? 127 : 126) - 2 * slot;   // heavy-first, parity split
    int qb = qt * 16;

    int tid = threadIdx.x;
    int w = tid >> 6;                   // 0..7
    int lane = tid & 63;
    int g = lane >> 4;
    int c16 = lane & 15;

    const __bf16* qsb = qs + (size_t)(b * TSEQ + qb) * HEAD;
    const __bf16* kb_ = ks + (size_t)b * TSEQ * HEAD;
    const __bf16* vb_ = vT + (size_t)b * HEAD * TSEQ;

    bf16x8 qf0 = *(const bf16x8*)(qsb + c16 * HEAD + g * 8);
    bf16x8 qf1 = *(const bf16x8*)(qsb + c16 * HEAD + 32 + g * 8);

    f32x4 o0 = {0.f, 0.f, 0.f, 0.f}, o1 = o0, o2 = o0, o3 = o0;
    float m = -3.0e38f, l = 0.f;

    int nt = (qb + 47) >> 5;            // number of 32-key tiles
    int qrow = qb + c16;

    bf16x8 k00c, k01c, k10c, k11c;
    if (w < nt) {
        const __bf16* kr0 = kb_ + (size_t)(w * 32 + c16) * HEAD + g * 8;
        k00c = *(const bf16x8*)(kr0);
        k01c = *(const bf16x8*)(kr0 + 32);
        const __bf16* kr1 = kr0 + 16 * HEAD;
        k10c = *(const bf16x8*)(kr1);
        k11c = *(const bf16x8*)(kr1 + 32);
    }

    for (int ti = w; ti < nt; ti += 8) {
        int kbase = ti * 32;

        const __bf16* vbase = vb_ + kbase + g * 8;
        bf16x8 v0 = *(const bf16x8*)(vbase + (size_t)(c16) * TSEQ);
        bf16x8 v1 = *(const bf16x8*)(vbase + (size_t)(c16 + 16) * TSEQ);
        bf16x8 v2 = *(const bf16x8*)(vbase + (size_t)(c16 + 32) * TSEQ);
        bf16x8 v3 = *(const bf16x8*)(vbase + (size_t)(c16 + 48) * TSEQ);

        bool pf = (ti + 8) < nt;
        bf16x8 k00n, k01n, k10n, k11n;
        if (pf) {
            const __bf16* kr0 = kb_ + (size_t)(kbase + 256 + c16) * HEAD + g * 8;
            k00n = *(const bf16x8*)(kr0);
            k01n = *(const bf16x8*)(kr0 + 32);
            const __bf16* kr1 = kr0 + 16 * HEAD;
            k10n = *(const bf16x8*)(kr1);
            k11n = *(const bf16x8*)(kr1 + 32);
        }

        f32x4 z = {0.f, 0.f, 0.f, 0.f};
        f32x4 s0 = __builtin_amdgcn_mfma_f32_16x16x32_bf16(k00c, qf0, z, 0, 0, 0);
        s0 = __builtin_amdgcn_mfma_f32_16x16x32_bf16(k01c, qf1, s0, 0, 0, 0);
        f32x4 s1 = __builtin_amdgcn_mfma_f32_16x16x32_bf16(k10c, qf0, z, 0, 0, 0);
        s1 = __builtin_amdgcn_mfma_f32_16x16x32_bf16(k11c, qf1, s1, 0, 0, 0);

        if (kbase + 31 > qb) {
#pragma unroll
            for (int r = 0; r < 4; ++r) {
                if (kbase + 4 * g + r > qrow)      s0[r] = -3.0e38f;
                if (kbase + 16 + 4 * g + r > qrow) s1[r] = -3.0e38f;
            }
        }

        float vmax = fmaxf(fmaxf(fmaxf(s0[0], s0[1]), fmaxf(s0[2], s0[3])),
                           fmaxf(fmaxf(s1[0], s1[1]), fmaxf(s1[2], s1[3])));
        vmax = fmaxf(vmax, __shfl_xor(vmax, 16, 64));
        vmax = fmaxf(vmax, __shfl_xor(vmax, 32, 64));
        float mn = fmaxf(m, vmax);
        float al = exp2f(m - mn);
        m = mn;

        float p0[4], p1[4];
        float rsum = 0.f;
#pragma unroll
        for (int r = 0; r < 4; ++r) {
            p0[r] = exp2f(s0[r] - m);
            p1[r] = exp2f(s1[r] - m);
            rsum += p0[r] + p1[r];
        }
        rsum += __shfl_xor(rsum, 16, 64);
        rsum += __shfl_xor(rsum, 32, 64);
        l = l * al + rsum;
        o0 *= al; o1 *= al; o2 *= al; o3 *= al;

        unsigned pk[4];
        pk[0] = pkbf(p0[0], p0[1]); pk[1] = pkbf(p0[2], p0[3]);
        pk[2] = pkbf(p1[0], p1[1]); pk[3] = pkbf(p1[2], p1[3]);

        union { unsigned u[4]; bf16x8 v; } pb;
#pragma unroll
        for (int t = 0; t < 4; ++t) {
            int srcl = c16 + 16 * ((2 * g + (t >> 1)) & 3);
            unsigned lo = (unsigned)__shfl((int)pk[t & 1], srcl, 64);
            unsigned hi = (unsigned)__shfl((int)pk[2 + (t & 1)], srcl, 64);
            pb.u[t] = (g < 2) ? lo : hi;
        }

        o0 = __builtin_amdgcn_mfma_f32_16x16x32_bf16(v0, pb.v, o0, 0, 0, 0);
        o1 = __builtin_amdgcn_mfma_f32_16x16x32_bf16(v1, pb.v, o1, 0, 0, 0);
        o2 = __builtin_amdgcn_mfma_f32_16x16x32_bf16(v2, pb.v, o2, 0, 0, 0);
        o3 = __builtin_amdgcn_mfma_f32_16x16x32_bf16(v3, pb.v, o3, 0, 0, 0);

        if (pf) { k00c = k00n; k01c = k01n; k10c = k10n; k11c = k11n; }
    }

    ocomb[w][0][lane] = o0;
    ocomb[w][1][lane] = o1;
    ocomb[w][2][lane] = o2;
    ocomb[w][3][lane] = o3;
    if (g == 0) {
        mcomb[w][c16] = m;
        lcomb[w][c16] = l;
    }
    __syncthreads();

    if (w < 4) {
        float M = mcomb[0][c16];
#pragma unroll
        for (int sw = 1; sw < 8; ++sw) M = fmaxf(M, mcomb[sw][c16]);
        f32x4 O = {0.f, 0.f, 0.f, 0.f};
        float L = 0.f;
#pragma unroll
        for (int sw = 0; sw < 8; ++sw) {
            float e = exp2f(mcomb[sw][c16] - M);
            L += lcomb[sw][c16] * e;
            f32x4 po = ocomb[sw][w][lane];
            O[0] += po[0] * e; O[1] += po[1] * e;
            O[2] += po[2] * e; O[3] += po[3] * e;
        }
        float rcp = 1.0f / L;
        f32x4 res = {O[0] * rcp, O[1] * rcp, O[2] * rcp, O[3] * rcp};
        *(f32x4*)(out + (size_t)(b * TSEQ + qb + c16) * HEAD + w * 16 + g * 4) = res;
    }
}

extern "C" void kernel_launch(void* const* d_in, const int* in_sizes, int n_in,
                              void* d_out, int out_size, void* d_ws, size_t ws_size,
                              hipStream_t stream) {
    const float* x  = (const float*)d_in[0];
    const float* Wk = (const float*)d_in[1];
    const float* Wq = (const float*)d_in[2];
    const float* Wv = (const float*)d_in[3];
    const float* bk = (const float*)d_in[4];
    const float* bq = (const float*)d_in[5];
    const float* bv = (const float*)d_in[6];
    float* out = (float*)d_out;

    __bf16* qs  = (__bf16*)d_ws;                       // [BT][64]        1 MB
    __bf16* ks  = qs + (size_t)BT * HEAD;              // [BT][64]        1 MB
    __bf16* vT  = ks + (size_t)BT * HEAD;              // [NB][64][TSEQ]  1 MB
    __bf16* wtf = vT + (size_t)BT * HEAD;              // [12][32][64][8] 384 KB

    wt_kernel<<<48, 256, 0, stream>>>(Wq, Wk, Wv, wtf);
    qkv_gemm<<<1024, 512, 0, stream>>>(x, wtf, bq, bk, bv, qs, ks, vT);
    attn_mfma<<<512, 512, 0, stream>>>(qs, ks, vT, out);
}

// Round 17
// 36.331 us; speedup vs baseline: 2.6168x; 1.3667x over previous
//
#include <hip/hip_runtime.h>
#include <hip/hip_bf16.h>

#define D_MODEL 1024
#define HEAD 64
#define TSEQ 2048
#define NB 4
#define BT (NB * TSEQ)

typedef __bf16 bf16x8 __attribute__((ext_vector_type(8)));
typedef __bf16 bf16x4 __attribute__((ext_vector_type(4)));
typedef float f32x4 __attribute__((ext_vector_type(4)));

#define LOG2E 1.44269504088896f

__device__ inline unsigned pkbf(float a, float b) {
    union { __bf16 h[2]; unsigned u; } t;
    t.h[0] = (__bf16)a; t.h[1] = (__bf16)b;
    return t.u;
}

// ---------------------------------------------------------------------------
// Kernel 0: W -> B-fragment-major bf16 (unchanged from round 16).
// ---------------------------------------------------------------------------
__global__ __launch_bounds__(256) void wt_kernel(
    const float* __restrict__ Wq, const float* __restrict__ Wk,
    const float* __restrict__ Wv, __bf16* __restrict__ wtf)
{
    __shared__ float ws_[256][20];

    int jt = blockIdx.x >> 2;        // 0..11
    int chunk = blockIdx.x & 3;      // 0..3
    int tsel = jt >> 2;
    int colbase = (jt & 3) * 16;
    const float* W = tsel == 0 ? Wq : (tsel == 1 ? Wk : Wv);

    int t = threadIdx.x;
#pragma unroll
    for (int i = 0; i < 4; ++i) {
        int f4 = t + 256 * i;
        int krow = f4 >> 2, cg = f4 & 3;
        float4 v = *(const float4*)(W + (size_t)(chunk * 256 + krow) * 64 + colbase + cg * 4);
        *(float4*)(&ws_[krow][cg * 4]) = v;
    }
    __syncthreads();

#pragma unroll
    for (int sidx = 0; sidx < 2; ++sidx) {
        int s = t + 256 * sidx;
        int kk = s >> 6;
        int lane = s & 63;
        int c16 = lane & 15, g = lane >> 4;
        bf16x8 o;
#pragma unroll
        for (int i = 0; i < 8; ++i)
            o[i] = (__bf16)ws_[kk * 32 + g * 8 + i][c16];
        *(bf16x8*)(wtf + ((size_t)(jt * 32 + chunk * 8 + kk) * 64 + lane) * 8) = o;
    }
}

// ---------------------------------------------------------------------------
// Kernel 1 (ROUND 17): QKV GEMM — loads as round 16 (coalesced), epilogue now
// writes K and V FRAGMENT-MAJOR for attn:
//   kf[b][ti][f][lane][8]: f = 2*((t>>4)&1) + (h>>5);
//       lane = (t&15) + 16*((h&31)>>3); i = h&7     (A-frag of swapped QK^T)
//   vf[b][ti][hh][lane][8]: hh = h>>4;
//       lane = (h&15) + 16*((t&31)>>3); i = t&7     (A-frag of PV: V^T)
// Every attn K/V fragment load becomes a contiguous 1 KB wave load (was
// 64-line scatter — same disease R16 cured in qkv, −15 µs).
// ---------------------------------------------------------------------------
#define XPITCH 1032   // 1024 + 8 bf16 pad

__global__ __launch_bounds__(512, 4) void qkv_gemm(
    const float* __restrict__ x, const __bf16* __restrict__ wtf,
    const float* __restrict__ bq, const float* __restrict__ bk, const float* __restrict__ bv,
    __bf16* __restrict__ qs, __bf16* __restrict__ kf, __bf16* __restrict__ vf)
{
    __shared__ __align__(16) char lds_raw[49152];             // 48 KB
    __bf16 (*xls)[XPITCH] = (__bf16(*)[XPITCH])lds_raw;       // 33 KB (staging)
    f32x4 (*red)[6][64]   = (f32x4(*)[6][64])lds_raw;         // 48 KB (reduce)

    int d = blockIdx.x;
    int bi = d >> 3;
    int strip = (d & 7) * 64 + (bi >> 1);   // XCD-chunked rows
    int ch = bi & 1;
    int r0 = strip * 16;

    int tid = threadIdx.x;
    int w = tid >> 6;                 // 0..7 = K slice (128 k each)
    int lane = tid & 63;
    int c16 = lane & 15, g = lane >> 4;

    // ---- stage x[16][1024] -> LDS bf16, fully coalesced ----
#pragma unroll
    for (int i = 0; i < 8; ++i) {
        int f4 = tid + 512 * i;
        int row = f4 >> 8;
        int k = (f4 & 255) * 4;
        float4 v = *(const float4*)(x + (size_t)(r0 + row) * D_MODEL + k);
        bf16x4 o;
        o[0] = (__bf16)v.x; o[1] = (__bf16)v.y;
        o[2] = (__bf16)v.z; o[3] = (__bf16)v.w;
        *(bf16x4*)(&xls[row][k]) = o;
    }
    __syncthreads();

    f32x4 acc[6];
#pragma unroll
    for (int j = 0; j < 6; ++j) acc[j] = (f32x4){0.f, 0.f, 0.f, 0.f};

#pragma unroll
    for (int kt = 0; kt < 4; ++kt) {
        int ktile = w * 4 + kt;
        bf16x8 af = *(const bf16x8*)(&xls[c16][ktile * 32 + g * 8]);
        const __bf16* wb = wtf + ((size_t)ktile * 64 + lane) * 8;
#pragma unroll
        for (int j = 0; j < 6; ++j) {
            bf16x8 bfr = *(const bf16x8*)(wb + (size_t)(ch * 6 + j) * 32 * 64 * 8);
            acc[j] = __builtin_amdgcn_mfma_f32_16x16x32_bf16(af, bfr, acc[j], 0, 0, 0);
        }
    }

    __syncthreads();
#pragma unroll
    for (int j = 0; j < 6; ++j) red[w][j][lane] = acc[j];
    __syncthreads();

    if (w < 6) {
        int j = w;
        f32x4 s = red[0][j][lane];
#pragma unroll
        for (int sw = 1; sw < 8; ++sw) s += red[sw][j][lane];

        int col = ch * 96 + j * 16 + c16;   // global column 0..191
        int tsel = col >> 6;                // 0=q 1=k 2=v
        int cm = col & 63;
        const float* bias = tsel == 0 ? bq : (tsel == 1 ? bk : bv);
        float bval = bias[cm];

        int row0 = r0 + g * 4;              // first of 4 rows
        int b = row0 >> 11;
        int tloc = row0 & (TSEQ - 1);       // 4 consecutive, same tile half
        int ti = tloc >> 5;
        int fraghalf = (tloc >> 4) & 1;

        if (tsel == 0) {
#pragma unroll
            for (int r = 0; r < 4; ++r)
                qs[(size_t)(row0 + r) * HEAD + cm] = (__bf16)((s[r] + bval) * (0.03125f * LOG2E));
        } else if (tsel == 1) {
            // K fragment-major: f = 2*fraghalf + (cm>>5); lane' = (t&15) + 16*((cm&31)>>3); i = cm&7
            int f = 2 * fraghalf + (cm >> 5);
            int gk = (cm & 31) >> 3;
            int ik = cm & 7;
            __bf16* base = kf + (((size_t)(b * 64 + ti) * 4 + f) * 64) * 8 + ik;
#pragma unroll
            for (int r = 0; r < 4; ++r)
                base[(size_t)((g * 4 + r) + 16 * gk) * 8] = (__bf16)(s[r] + bval);
        } else {
            // V fragment-major: hh = cm>>4; lane' = (cm&15) + 16*g'; g' = 2*fraghalf + (g>>1); i = (g&1)*4 + r
            int hh = cm >> 4;
            int gp = 2 * fraghalf + (g >> 1);
            bf16x4 o;
#pragma unroll
            for (int r = 0; r < 4; ++r) o[r] = (__bf16)(s[r] + bval);
            *(bf16x4*)(vf + (((size_t)(b * 64 + ti) * 4 + hh) * 64 + (cm & 15) + 16 * gp) * 8 + (g & 1) * 4) = o;
        }
    }
}

// ---------------------------------------------------------------------------
// Kernel 2 (ROUND 17): flash attention — K/V loads now contiguous 1 KB
// wave loads from fragment-major kf/vf. Structure otherwise = round 12/14.
// ---------------------------------------------------------------------------
__global__ __launch_bounds__(512, 4) void attn_mfma(
    const __bf16* __restrict__ qs, const __bf16* __restrict__ kf,
    const __bf16* __restrict__ vf, float* __restrict__ out)
{
    __shared__ __align__(16) f32x4 ocomb[8][4][64];     // 32 KB [wave][hh][lane]
    __shared__ float mcomb[8][16];                      // [wave][qrow]
    __shared__ float lcomb[8][16];

    int d = blockIdx.x;
    int xcd = d & 7;
    int slot = d >> 3;                  // 0..63
    int b = xcd >> 1;
    int qt = ((xcd & 1) ? 127 : 126) - 2 * slot;   // heavy-first, parity split
    int qb = qt * 16;

    int tid = threadIdx.x;
    int w = tid >> 6;                   // 0..7
    int lane = tid & 63;
    int g = lane >> 4;
    int c16 = lane & 15;

    const __bf16* qsb = qs + (size_t)(b * TSEQ + qb) * HEAD;
    const __bf16* kfb = kf + (size_t)(b * 64) * 4 * 512;   // per-batch frag base
    const __bf16* vfb = vf + (size_t)(b * 64) * 4 * 512;

    bf16x8 qf0 = *(const bf16x8*)(qsb + c16 * HEAD + g * 8);
    bf16x8 qf1 = *(const bf16x8*)(qsb + c16 * HEAD + 32 + g * 8);

    f32x4 o0 = {0.f, 0.f, 0.f, 0.f}, o1 = o0, o2 = o0, o3 = o0;
    float m = -3.0e38f, l = 0.f;

    int nt = (qb + 47) >> 5;            // number of 32-key tiles
    int qrow = qb + c16;

    // ---- preload K for first tile (4 contiguous 1 KB wave loads) ----
    bf16x8 k00c, k01c, k10c, k11c;
    if (w < nt) {
        const __bf16* kt_ = kfb + (size_t)w * 4 * 512 + lane * 8;
        k00c = *(const bf16x8*)(kt_);
        k01c = *(const bf16x8*)(kt_ + 512);
        k10c = *(const bf16x8*)(kt_ + 1024);
        k11c = *(const bf16x8*)(kt_ + 1536);
    }

    for (int ti = w; ti < nt; ti += 8) {
        int kbase = ti * 32;

        // ---- early-issue V for this tile (contiguous) ----
        const __bf16* vt_ = vfb + (size_t)ti * 4 * 512 + lane * 8;
        bf16x8 v0 = *(const bf16x8*)(vt_);
        bf16x8 v1 = *(const bf16x8*)(vt_ + 512);
        bf16x8 v2 = *(const bf16x8*)(vt_ + 1024);
        bf16x8 v3 = *(const bf16x8*)(vt_ + 1536);

        // ---- prefetch next K tile (contiguous) ----
        bool pf = (ti + 8) < nt;
        bf16x8 k00n, k01n, k10n, k11n;
        if (pf) {
            const __bf16* kn_ = kfb + (size_t)(ti + 8) * 4 * 512 + lane * 8;
            k00n = *(const bf16x8*)(kn_);
            k01n = *(const bf16x8*)(kn_ + 512);
            k10n = *(const bf16x8*)(kn_ + 1024);
            k11n = *(const bf16x8*)(kn_ + 1536);
        }

        // ---- QK^T (swapped) ----
        f32x4 z = {0.f, 0.f, 0.f, 0.f};
        f32x4 s0 = __builtin_amdgcn_mfma_f32_16x16x32_bf16(k00c, qf0, z, 0, 0, 0);
        s0 = __builtin_amdgcn_mfma_f32_16x16x32_bf16(k01c, qf1, s0, 0, 0, 0);
        f32x4 s1 = __builtin_amdgcn_mfma_f32_16x16x32_bf16(k10c, qf0, z, 0, 0, 0);
        s1 = __builtin_amdgcn_mfma_f32_16x16x32_bf16(k11c, qf1, s1, 0, 0, 0);

        // ---- causal mask ----
        if (kbase + 31 > qb) {
#pragma unroll
            for (int r = 0; r < 4; ++r) {
                if (kbase + 4 * g + r > qrow)      s0[r] = -3.0e38f;
                if (kbase + 16 + 4 * g + r > qrow) s1[r] = -3.0e38f;
            }
        }

        // ---- online softmax ----
        float vmax = fmaxf(fmaxf(fmaxf(s0[0], s0[1]), fmaxf(s0[2], s0[3])),
                           fmaxf(fmaxf(s1[0], s1[1]), fmaxf(s1[2], s1[3])));
        vmax = fmaxf(vmax, __shfl_xor(vmax, 16, 64));
        vmax = fmaxf(vmax, __shfl_xor(vmax, 32, 64));
        float mn = fmaxf(m, vmax);
        float al = exp2f(m - mn);
        m = mn;

        float p0[4], p1[4];
        float rsum = 0.f;
#pragma unroll
        for (int r = 0; r < 4; ++r) {
            p0[r] = exp2f(s0[r] - m);
            p1[r] = exp2f(s1[r] - m);
            rsum += p0[r] + p1[r];
        }
        rsum += __shfl_xor(rsum, 16, 64);
        rsum += __shfl_xor(rsum, 32, 64);
        l = l * al + rsum;
        o0 *= al; o1 *= al; o2 *= al; o3 *= al;

        // ---- P^T redistribution ----
        unsigned pk[4];
        pk[0] = pkbf(p0[0], p0[1]); pk[1] = pkbf(p0[2], p0[3]);
        pk[2] = pkbf(p1[0], p1[1]); pk[3] = pkbf(p1[2], p1[3]);

        union { unsigned u[4]; bf16x8 v; } pb;
#pragma unroll
        for (int t = 0; t < 4; ++t) {
            int srcl = c16 + 16 * ((2 * g + (t >> 1)) & 3);
            unsigned lo = (unsigned)__shfl((int)pk[t & 1], srcl, 64);
            unsigned hi = (unsigned)__shfl((int)pk[2 + (t & 1)], srcl, 64);
            pb.u[t] = (g < 2) ? lo : hi;
        }

        // ---- PV ----
        o0 = __builtin_amdgcn_mfma_f32_16x16x32_bf16(v0, pb.v, o0, 0, 0, 0);
        o1 = __builtin_amdgcn_mfma_f32_16x16x32_bf16(v1, pb.v, o1, 0, 0, 0);
        o2 = __builtin_amdgcn_mfma_f32_16x16x32_bf16(v2, pb.v, o2, 0, 0, 0);
        o3 = __builtin_amdgcn_mfma_f32_16x16x32_bf16(v3, pb.v, o3, 0, 0, 0);

        if (pf) { k00c = k00n; k01c = k01n; k10c = k10n; k11c = k11n; }
    }

    // ---- publish partials ----
    ocomb[w][0][lane] = o0;
    ocomb[w][1][lane] = o1;
    ocomb[w][2][lane] = o2;
    ocomb[w][3][lane] = o3;
    if (g == 0) {
        mcomb[w][c16] = m;
        lcomb[w][c16] = l;
    }
    __syncthreads();

    // ---- combine ----
    if (w < 4) {
        float M = mcomb[0][c16];
#pragma unroll
        for (int sw = 1; sw < 8; ++sw) M = fmaxf(M, mcomb[sw][c16]);
        f32x4 O = {0.f, 0.f, 0.f, 0.f};
        float L = 0.f;
#pragma unroll
        for (int sw = 0; sw < 8; ++sw) {
            float e = exp2f(mcomb[sw][c16] - M);
            L += lcomb[sw][c16] * e;
            f32x4 po = ocomb[sw][w][lane];
            O[0] += po[0] * e; O[1] += po[1] * e;
            O[2] += po[2] * e; O[3] += po[3] * e;
        }
        float rcp = 1.0f / L;
        f32x4 res = {O[0] * rcp, O[1] * rcp, O[2] * rcp, O[3] * rcp};
        *(f32x4*)(out + (size_t)(b * TSEQ + qb + c16) * HEAD + w * 16 + g * 4) = res;
    }
}

extern "C" void kernel_launch(void* const* d_in, const int* in_sizes, int n_in,
                              void* d_out, int out_size, void* d_ws, size_t ws_size,
                              hipStream_t stream) {
    const float* x  = (const float*)d_in[0];
    const float* Wk = (const float*)d_in[1];
    const float* Wq = (const float*)d_in[2];
    const float* Wv = (const float*)d_in[3];
    const float* bk = (const float*)d_in[4];
    const float* bq = (const float*)d_in[5];
    const float* bv = (const float*)d_in[6];
    float* out = (float*)d_out;

    __bf16* qs  = (__bf16*)d_ws;                       // [BT][64]          1 MB
    __bf16* kf  = qs + (size_t)BT * HEAD;              // [NB][64][4][64][8] 1 MB
    __bf16* vf  = kf + (size_t)BT * HEAD;              // [NB][64][4][64][8] 1 MB
    __bf16* wtf = vf + (size_t)BT * HEAD;              // [12][32][64][8]  384 KB

    wt_kernel<<<48, 256, 0, stream>>>(Wq, Wk, Wv, wtf);
    qkv_gemm<<<1024, 512, 0, stream>>>(x, wtf, bq, bk, bv, qs, kf, vf);
    attn_mfma<<<512, 512, 0, stream>>>(qs, kf, vf, out);
}